// Round 5
// baseline (786.440 us; speedup 1.0000x reference)
//
#include <hip/hip_runtime.h>

// Problem constants
#define B_   2
#define S_   2048
#define D_   2048
#define H_   16
#define HKV_ 4
#define HD_  128
#define SCALE_ 0.08838834764831845f  // 128^-0.5

typedef unsigned short u16;
typedef unsigned int u32;
typedef __attribute__((ext_vector_type(4))) float  f32x4;
typedef __attribute__((ext_vector_type(8))) __bf16 bf16x8;

__device__ __forceinline__ u16 f2b(float f) {
  u32 u = __builtin_bit_cast(u32, f);
  u += 0x7fffu + ((u >> 16) & 1u);   // round-to-nearest-even
  return (u16)(u >> 16);
}
__device__ __forceinline__ __bf16 f2bf(float f) {
  u16 b = f2b(f);
  return __builtin_bit_cast(__bf16, b);
}

// ---------------- fp32 -> bf16 elementwise (x) ----------------
__global__ void k_f2b(const float* __restrict__ in, u16* __restrict__ out) {
  size_t i = (size_t)blockIdx.x * 256 + threadIdx.x;
  float4 v = reinterpret_cast<const float4*>(in)[i];
  ushort4 o;
  o.x = f2b(v.x); o.y = f2b(v.y); o.z = f2b(v.z); o.w = f2b(v.w);
  reinterpret_cast<ushort4*>(out)[i] = o;
}

// ---------------- init: zero lsum (B*H*S) and knm (8) ----------------
__global__ void k_init(float* __restrict__ lsum, u32* __restrict__ knm) {
  int i = blockIdx.x * 256 + threadIdx.x;
  if (i < B_ * H_ * S_) lsum[i] = 0.f;
  if (i < B_ * HKV_) knm[i] = 0u;
}

// ---------------- W[K][N] fp32 -> Wt[N][K] bf16 (tiled transpose) ----------------
__global__ void k_wT(const float* __restrict__ W, u16* __restrict__ Wt, int K, int N) {
  __shared__ float t[32][33];
  int n0 = blockIdx.x * 32, k0 = blockIdx.y * 32;
  int tx = threadIdx.x, ty = threadIdx.y;
  for (int j = ty; j < 32; j += 8)
    t[j][tx] = W[(size_t)(k0 + j) * N + n0 + tx];
  __syncthreads();
  for (int j = ty; j < 32; j += 8)
    Wt[(size_t)(n0 + j) * K + k0 + tx] = f2b(t[tx][j]);
}

// ---------------- GEMM: C[M][N] fp32 = A[M][K] bf16 * Bt[N][K] bf16 ----------------
__global__ __launch_bounds__(256, 3)
void k_gemm(const u16* __restrict__ A, const u16* __restrict__ Bt,
            float* __restrict__ C, int M, int N, int K) {
  __shared__ char smem[128 * 128 + 128 * 128];
  char* As = smem;
  char* Bs = smem + 128 * 128;
  const int tid = threadIdx.x;
  const int lane = tid & 63, wave = tid >> 6;
  const int l16 = lane & 15, lhi = lane >> 4;
  const int wm = (wave >> 1) * 64, wn = (wave & 1) * 64;
  const int bm = blockIdx.y, bn = blockIdx.x;
  const u16* Ab = A + (size_t)bm * 128 * K;
  const u16* Bb = Bt + (size_t)bn * 128 * K;
  f32x4 acc[4][4] = {};
  for (int k0 = 0; k0 < K; k0 += 64) {
    for (int p = 0; p < 4; ++p) {
      int r0 = wave * 32 + p * 8;
      int row = r0 + (lane >> 3);
      int src_off = ((lane & 7) * 16) ^ ((row & 7) << 4);
      const char* ga = (const char*)(Ab + (size_t)row * K + k0) + src_off;
      const char* gb = (const char*)(Bb + (size_t)row * K + k0) + src_off;
      __builtin_amdgcn_global_load_lds(
          (const __attribute__((address_space(1))) void*)ga,
          (__attribute__((address_space(3))) void*)(As + r0 * 128), 16, 0, 0);
      __builtin_amdgcn_global_load_lds(
          (const __attribute__((address_space(1))) void*)gb,
          (__attribute__((address_space(3))) void*)(Bs + r0 * 128), 16, 0, 0);
    }
    __syncthreads();
    for (int ks = 0; ks < 2; ++ks) {
      bf16x8 af[4], bfr[4];
      for (int f = 0; f < 4; ++f) {
        int m = wm + f * 16 + l16;
        af[f] = *reinterpret_cast<const bf16x8*>(As + m * 128 + ((ks * 64 + lhi * 16) ^ ((m & 7) << 4)));
        int n = wn + f * 16 + l16;
        bfr[f] = *reinterpret_cast<const bf16x8*>(Bs + n * 128 + ((ks * 64 + lhi * 16) ^ ((n & 7) << 4)));
      }
      for (int i = 0; i < 4; ++i)
        for (int j = 0; j < 4; ++j)
          acc[i][j] = __builtin_amdgcn_mfma_f32_16x16x32_bf16(af[i], bfr[j], acc[i][j], 0, 0, 0);
    }
    __syncthreads();
  }
  for (int i = 0; i < 4; ++i) {
    int m0 = bm * 128 + wm + i * 16 + lhi * 4;
    for (int j = 0; j < 4; ++j) {
      int n0 = bn * 128 + wn + j * 16 + l16;
      for (int r = 0; r < 4; ++r)
        C[(size_t)(m0 + r) * N + n0] = acc[i][j][r];
    }
  }
}

// ---------------- RoPE + row-norm capture ----------------
__global__ void k_rope(const float* __restrict__ pre, const float* __restrict__ cosT,
                       const float* __restrict__ sinT, u16* __restrict__ outb,
                       float* __restrict__ qn, u32* __restrict__ kn2max,
                       int nh, int rowstride) {
  int idx = blockIdx.x;          // (b*S + s)*nh + h
  int h = idx % nh;
  int bs = idx / nh;
  int b = bs / S_, s = bs % S_;
  int d = threadIdx.x;           // 0..63
  const float* row = pre + (size_t)bs * rowstride + h * HD_;
  const float* cr = cosT + (size_t)bs * HD_;
  const float* sr = sinT + (size_t)bs * HD_;
  float v1 = row[d], v2 = row[d + 64];
  float c1 = cr[d], s1 = sr[d], c2 = cr[d + 64], s2 = sr[d + 64];
  u16* out = outb + (((size_t)b * nh + h) * S_ + s) * HD_;
  out[d]      = f2b(v1 * c1 - v2 * s1);
  out[d + 64] = f2b(v2 * c2 + v1 * s2);
  float nr2 = v1 * v1 + v2 * v2;
  for (int o = 1; o < 64; o <<= 1) nr2 += __shfl_xor(nr2, o);
  if (d == 0) {
    if (qn)     qn[((size_t)b * nh + h) * S_ + s] = sqrtf(nr2);
    if (kn2max) atomicMax(&kn2max[b * nh + h], __builtin_bit_cast(u32, nr2));
  }
}

// ---------------- V: kvpre[B*S][1024] cols 512.. fp32 -> vT[(b*HKV+h)*128+d][S] bf16 ----------------
__global__ void k_vT(const float* __restrict__ kvpre, u16* __restrict__ vT) {
  __shared__ float t[32][33];
  int s0 = blockIdx.x * 32, d0 = blockIdx.y * 32;
  int bh = blockIdx.z;
  int b = bh >> 2, hk = bh & 3;
  int tx = threadIdx.x, ty = threadIdx.y;
  for (int j = ty; j < 32; j += 8)
    t[j][tx] = kvpre[((size_t)b * S_ + s0 + j) * 1024 + 512 + hk * HD_ + d0 + tx];
  __syncthreads();
  for (int j = ty; j < 32; j += 8)
    vT[((size_t)bh * HD_ + d0 + j) * S_ + s0 + tx] = f2b(t[tx][j]);
}

// ---------------- k_scores: one 128x128 lower-tri tile of exp(QK^T*s - M) ----------------
// Writes unnormalized p (fp32) into attn; atomicAdd row-sums into lsum.
__global__ __launch_bounds__(256, 2)
void k_scores(const u16* __restrict__ qb_, const u16* __restrict__ kb_,
              const float* __restrict__ qn, const u32* __restrict__ knm,
              float* __restrict__ attn, float* __restrict__ lsum) {
  __shared__ char smem[65536];        // Qs 32KB + Ks 32KB (rows 256B, swizzled)
  __shared__ float red[4][64];
  __shared__ float qnl[128];
  char* Qs = smem;
  char* Ks = smem + 32768;
  const int tid = threadIdx.x;
  const int lane = tid & 63, wave = tid >> 6;
  const int l16 = lane & 15, lhi = lane >> 4;
  const int wm = (wave >> 1) * 64, wn = (wave & 1) * 64;

  const int bid = blockIdx.x;
  const int bh = bid / 136;
  int t = bid - bh * 136;
  int qbi = (int)((sqrtf(8.f * (float)t + 1.f) - 1.f) * 0.5f);
  while ((qbi + 1) * (qbi + 2) / 2 <= t) ++qbi;
  while (qbi * (qbi + 1) / 2 > t) --qbi;
  const int kbi = t - qbi * (qbi + 1) / 2;
  const int b = bh >> 4, h = bh & 15, hk = h >> 2;
  const int q0 = qbi * 128, k0 = kbi * 128;
  const bool diag = (qbi == kbi);

  const u16* Q = qb_ + ((size_t)(b * H_ + h) * S_ + q0) * HD_;
  const u16* K = kb_ + ((size_t)(b * HKV_ + hk) * S_ + k0) * HD_;
  float* attnp = attn + ((size_t)(b * H_ + h) * S_ + q0) * S_ + k0;

  if (tid < 128) qnl[tid] = qn[((size_t)b * H_ + h) * S_ + q0 + tid];
  const float kmax = sqrtf(__builtin_bit_cast(float, knm[b * HKV_ + hk]));

  // stage Q and K tiles (128 rows x 256B each)
  for (int p = 0; p < 8; ++p) {
    int r0 = wave * 32 + p * 4;
    int row = r0 + (lane >> 4);
    int src_off = ((lane & 15) * 16) ^ ((row & 7) << 4);
    __builtin_amdgcn_global_load_lds(
        (const __attribute__((address_space(1))) void*)((const char*)(Q + (size_t)row * HD_) + src_off),
        (__attribute__((address_space(3))) void*)(Qs + r0 * 256), 16, 0, 0);
    __builtin_amdgcn_global_load_lds(
        (const __attribute__((address_space(1))) void*)((const char*)(K + (size_t)row * HD_) + src_off),
        (__attribute__((address_space(3))) void*)(Ks + r0 * 256), 16, 0, 0);
  }
  __syncthreads();

  f32x4 acc[4][4] = {};
  for (int kd = 0; kd < 4; ++kd) {
    bf16x8 af[4], bfr[4];
    #pragma unroll
    for (int f = 0; f < 4; ++f) {
      int m = wm + f * 16 + l16;
      af[f] = *reinterpret_cast<const bf16x8*>(Qs + m * 256 + ((kd * 64 + lhi * 16) ^ ((m & 7) << 4)));
      int n = wn + f * 16 + l16;
      bfr[f] = *reinterpret_cast<const bf16x8*>(Ks + n * 256 + ((kd * 64 + lhi * 16) ^ ((n & 7) << 4)));
    }
    #pragma unroll
    for (int i = 0; i < 4; ++i)
      #pragma unroll
      for (int j = 0; j < 4; ++j)
        acc[i][j] = __builtin_amdgcn_mfma_f32_16x16x32_bf16(af[i], bfr[j], acc[i][j], 0, 0, 0);
  }

  // exp + optional diag mask + store + rowsum
  #pragma unroll
  for (int i = 0; i < 4; ++i) {
    float rs[4] = {0.f, 0.f, 0.f, 0.f};
    float Mr[4];
    #pragma unroll
    for (int r = 0; r < 4; ++r)
      Mr[r] = SCALE_ * kmax * qnl[wm + i * 16 + lhi * 4 + r];
    #pragma unroll
    for (int j = 0; j < 4; ++j) {
      #pragma unroll
      for (int r = 0; r < 4; ++r) {
        float p = __expf(acc[i][j][r] * SCALE_ - Mr[r]);
        if (diag) {
          int rowi = wm + i * 16 + lhi * 4 + r;
          int coli = wn + j * 16 + l16;
          p = (coli > rowi) ? 0.f : p;
        }
        acc[i][j][r] = p;
        rs[r] += p;
      }
    }
    #pragma unroll
    for (int j = 0; j < 4; ++j)
      #pragma unroll
      for (int r = 0; r < 4; ++r)
        attnp[(size_t)(wm + i * 16 + lhi * 4 + r) * S_ + wn + j * 16 + l16] = acc[i][j][r];
    #pragma unroll
    for (int r = 0; r < 4; ++r) {
      float s = rs[r];
      s += __shfl_xor(s, 1); s += __shfl_xor(s, 2);
      s += __shfl_xor(s, 4); s += __shfl_xor(s, 8);
      if (l16 == 0) red[wave][i * 16 + lhi * 4 + r] = s;
    }
  }
  __syncthreads();
  if (tid < 128) {
    int w0 = (tid >> 6) * 2;
    float s = red[w0][tid & 63] + red[w0 + 1][tid & 63];
    atomicAdd(&lsum[(size_t)bh * S_ + q0 + tid], s);
  }
}

// ---------------- k_pv: PV GEMM + in-place attn normalize + zero-fill ----------------
// Block = (bh, qb). Reads unnormalized p from attn, writes normalized back,
// accumulates (p/l)*V -> oh. qb remapped so CU-resident pairs have equal work.
__global__ __launch_bounds__(256, 2)
void k_pv(float* __restrict__ attn, const u16* __restrict__ vT,
          const float* __restrict__ lsum, u16* __restrict__ oh) {
  __shared__ char smem[49152];       // As fp32 32KB (swizzled) + Vs bf16 16KB
  __shared__ float rl[128];
  char* As = smem;
  char* Vs = smem + 32768;
  const int tid = threadIdx.x;
  const int lane = tid & 63, wave = tid >> 6;
  const int l16 = lane & 15, lhi = lane >> 4;
  const int wm = (wave >> 1) * 64, wn = (wave & 1) * 64;

  const int slot = blockIdx.x >> 5;               // 0..15
  const int qbi = (slot < 8) ? slot : 23 - slot;  // pair long+short per CU
  const int bh = blockIdx.x & 31;
  const int b = bh >> 4, h = bh & 15, hk = h >> 2;
  const int q0 = qbi * 128;
  const int kend = (qbi + 1) * 128;

  float* attnp = attn + ((size_t)(b * H_ + h) * S_ + q0) * S_;
  const u16* Vt = vT + (size_t)(b * HKV_ + hk) * HD_ * S_;

  if (tid < 128) rl[tid] = 1.f / lsum[(size_t)bh * S_ + q0 + tid];
  __syncthreads();

  f32x4 acc[4][4] = {};
  for (int kt = 0; kt < kend; kt += 64) {
    // stage A (128x64 fp32): read, normalize, write back, ds_write swizzled
    #pragma unroll
    for (int p = 0; p < 8; ++p) {
      int row = (tid >> 4) + p * 16;
      int qd = tid & 15;
      float* gp = attnp + (size_t)row * S_ + kt + qd * 4;
      f32x4 v = *reinterpret_cast<const f32x4*>(gp);
      v *= rl[row];
      *reinterpret_cast<f32x4*>(gp) = v;
      int byte = row * 256 + (((((qd >> 1) ^ (row & 7)) << 5)) | ((qd & 1) << 4));
      *reinterpret_cast<f32x4*>(As + byte) = v;
    }
    // stage V^T tile (128 rows x 128B)
    #pragma unroll
    for (int p = 0; p < 4; ++p) {
      int r0 = wave * 32 + p * 8;
      int row = r0 + (lane >> 3);
      int src_off = ((lane & 7) * 16) ^ ((row & 7) << 4);
      __builtin_amdgcn_global_load_lds(
          (const __attribute__((address_space(1))) void*)((const char*)(Vt + (size_t)row * S_ + kt) + src_off),
          (__attribute__((address_space(3))) void*)(Vs + r0 * 128), 16, 0, 0);
    }
    __syncthreads();
    #pragma unroll
    for (int kd = 0; kd < 2; ++kd) {
      bf16x8 af[4], bfr[4];
      #pragma unroll
      for (int f = 0; f < 4; ++f) {
        int m = wm + f * 16 + l16;
        int chunk = (kd * 4 + lhi) ^ (m & 7);
        f32x4 a0 = *reinterpret_cast<const f32x4*>(As + m * 256 + (chunk << 5));
        f32x4 a1 = *reinterpret_cast<const f32x4*>(As + m * 256 + (chunk << 5) + 16);
        bf16x8 av;
        av[0] = f2bf(a0[0]); av[1] = f2bf(a0[1]); av[2] = f2bf(a0[2]); av[3] = f2bf(a0[3]);
        av[4] = f2bf(a1[0]); av[5] = f2bf(a1[1]); av[6] = f2bf(a1[2]); av[7] = f2bf(a1[3]);
        af[f] = av;
        int n = wn + f * 16 + l16;
        bfr[f] = *reinterpret_cast<const bf16x8*>(Vs + n * 128 + ((kd * 64 + lhi * 16) ^ ((n & 7) << 4)));
      }
      #pragma unroll
      for (int i = 0; i < 4; ++i)
        #pragma unroll
        for (int j = 0; j < 4; ++j)
          acc[i][j] = __builtin_amdgcn_mfma_f32_16x16x32_bf16(af[i], bfr[j], acc[i][j], 0, 0, 0);
    }
    __syncthreads();
  }

  // oh write (bf16): out rows q0+.., cols h*128+..
  #pragma unroll
  for (int i = 0; i < 4; ++i)
    #pragma unroll
    for (int j = 0; j < 4; ++j)
      #pragma unroll
      for (int r = 0; r < 4; ++r) {
        int row = q0 + wm + i * 16 + lhi * 4 + r;
        oh[((size_t)b * S_ + row) * (H_ * HD_) + h * HD_ + wn + j * 16 + l16] = f2b(acc[i][j][r]);
      }

  // zero-fill cols [kend, S)
  {
    f32x4 z = {0.f, 0.f, 0.f, 0.f};
    int row = tid >> 1, half = tid & 1;
    for (int c = kend + half * 4; c < S_; c += 8)
      *reinterpret_cast<f32x4*>(attnp + (size_t)row * S_ + c) = z;
  }
}

extern "C" void kernel_launch(void* const* d_in, const int* in_sizes, int n_in,
                              void* d_out, int out_size, void* d_ws, size_t ws_size,
                              hipStream_t stream) {
  const float* x    = (const float*)d_in[0];
  const float* cosT = (const float*)d_in[1];
  const float* sinT = (const float*)d_in[2];
  // d_in[3] = attention_mask: pure causal, reconstructed in-kernel
  const float* Wq = (const float*)d_in[4];
  const float* Wk = (const float*)d_in[5];
  const float* Wv = (const float*)d_in[6];
  const float* Wo = (const float*)d_in[7];
  float* out  = (float*)d_out;
  float* attn = out + (size_t)B_ * S_ * D_;

  char* ws = (char*)d_ws;
  u16*   xb    = (u16*)(ws);                       // 16,777,216 B
  u16*   wqT   = (u16*)(ws + 16777216);            //  8,388,608
  u16*   wkvT  = (u16*)(ws + 25165824);            //  4,194,304 (K rows 0..511, V rows 512..1023)
  u16*   woT   = (u16*)(ws + 29360128);            //  8,388,608
  float* qpre  = (float*)(ws + 37748736);          // 33,554,432
  float* kvpre = (float*)(ws + 71303168);          // 16,777,216
  u16*   qb    = (u16*)(ws + 88080384);            // 16,777,216
  u16*   kb    = (u16*)(ws + 104857600);           //  4,194,304
  u16*   vT    = (u16*)(ws + 109051904);           //  4,194,304
  u16*   oh    = (u16*)(ws + 113246208);           // 16,777,216
  float* lsum  = (float*)(ws + 130023424);         //    262,144 (B*H*S)
  u32*   knm   = (u32*)(ws + 130285568);           //         32
  // qn reuses xb region (xb dead after projection GEMMs; k_rope runs after)
  float* qn    = (float*)(ws);                     //    262,144

  // 1) dtype prep + init
  k_f2b<<<8192, 256, 0, stream>>>(x, xb);
  k_init<<<256, 256, 0, stream>>>(lsum, knm);
  k_wT<<<dim3(64, 64), dim3(32, 8), 0, stream>>>(Wq, wqT, 2048, 2048);
  k_wT<<<dim3(16, 64), dim3(32, 8), 0, stream>>>(Wk, wkvT, 2048, 512);
  k_wT<<<dim3(16, 64), dim3(32, 8), 0, stream>>>(Wv, wkvT + (size_t)512 * 2048, 2048, 512);
  k_wT<<<dim3(64, 64), dim3(32, 8), 0, stream>>>(Wo, woT, 2048, 2048);

  // 2) projections: Q (N=2048) and fused K|V (N=1024)
  k_gemm<<<dim3(16, 32), 256, 0, stream>>>(xb, wqT, qpre, 4096, 2048, 2048);
  k_gemm<<<dim3(8, 32), 256, 0, stream>>>(xb, wkvT, kvpre, 4096, 1024, 2048);

  // 3) RoPE + layout conversion (+ norm capture); xb is free now
  k_rope<<<B_ * S_ * H_, 64, 0, stream>>>(qpre, cosT, sinT, qb, qn, nullptr, H_, 2048);
  k_rope<<<B_ * S_ * HKV_, 64, 0, stream>>>(kvpre, cosT, sinT, kb, nullptr, knm, HKV_, 1024);
  k_vT<<<dim3(64, 4, B_ * HKV_), dim3(32, 8), 0, stream>>>(kvpre, vT);

  // 4a) scores: unnormalized p -> attn (lower tiles) + row-sums
  k_scores<<<32 * 136, 256, 0, stream>>>(qb, kb, qn, knm, attn, lsum);

  // 4b) PV + in-place normalize + zero-fill upper
  k_pv<<<512, 256, 0, stream>>>(attn, vT, lsum, oh);

  // 5) output projection
  k_gemm<<<dim3(16, 32), 256, 0, stream>>>(oh, woT, out, 4096, 2048, 2048);
}

// Round 6
// 678.309 us; speedup vs baseline: 1.1594x; 1.1594x over previous
//
#include <hip/hip_runtime.h>

// Problem constants
#define B_   2
#define S_   2048
#define D_   2048
#define H_   16
#define HKV_ 4
#define HD_  128
#define SCALE_ 0.08838834764831845f  // 128^-0.5

typedef unsigned short u16;
typedef unsigned int u32;
typedef __attribute__((ext_vector_type(4))) float  f32x4;
typedef __attribute__((ext_vector_type(8))) __bf16 bf16x8;

__device__ __forceinline__ u16 f2b(float f) {
  u32 u = __builtin_bit_cast(u32, f);
  u += 0x7fffu + ((u >> 16) & 1u);   // round-to-nearest-even
  return (u16)(u >> 16);
}

// ---------------- fp32 -> bf16 elementwise (x) ----------------
__global__ void k_f2b(const float* __restrict__ in, u16* __restrict__ out) {
  size_t i = (size_t)blockIdx.x * 256 + threadIdx.x;
  float4 v = reinterpret_cast<const float4*>(in)[i];
  ushort4 o;
  o.x = f2b(v.x); o.y = f2b(v.y); o.z = f2b(v.z); o.w = f2b(v.w);
  reinterpret_cast<ushort4*>(out)[i] = o;
}

// ---------------- tiny init: zero the 8 k-norm slots ----------------
__global__ void k_init8(u32* __restrict__ p) {
  if (threadIdx.x < 8) p[threadIdx.x] = 0u;
}

// ---------------- W[K][N] fp32 -> Wt[N][K] bf16 (tiled transpose) ----------------
__global__ void k_wT(const float* __restrict__ W, u16* __restrict__ Wt, int K, int N) {
  __shared__ float t[32][33];
  int n0 = blockIdx.x * 32, k0 = blockIdx.y * 32;
  int tx = threadIdx.x, ty = threadIdx.y;
  for (int j = ty; j < 32; j += 8)
    t[j][tx] = W[(size_t)(k0 + j) * N + n0 + tx];
  __syncthreads();
  for (int j = ty; j < 32; j += 8)
    Wt[(size_t)(n0 + j) * K + k0 + tx] = f2b(t[tx][j]);
}

// ---------------- GEMM: C[M][N] fp32 = A[M][K] bf16 * Bt[N][K] bf16 ----------------
__global__ __launch_bounds__(256, 3)
void k_gemm(const u16* __restrict__ A, const u16* __restrict__ Bt,
            float* __restrict__ C, int M, int N, int K) {
  __shared__ char smem[128 * 128 + 128 * 128];
  char* As = smem;
  char* Bs = smem + 128 * 128;
  const int tid = threadIdx.x;
  const int lane = tid & 63, wave = tid >> 6;
  const int l16 = lane & 15, lhi = lane >> 4;
  const int wm = (wave >> 1) * 64, wn = (wave & 1) * 64;
  const int bm = blockIdx.y, bn = blockIdx.x;
  const u16* Ab = A + (size_t)bm * 128 * K;
  const u16* Bb = Bt + (size_t)bn * 128 * K;
  f32x4 acc[4][4] = {};
  for (int k0 = 0; k0 < K; k0 += 64) {
    for (int p = 0; p < 4; ++p) {
      int r0 = wave * 32 + p * 8;
      int row = r0 + (lane >> 3);
      int src_off = ((lane & 7) * 16) ^ ((row & 7) << 4);
      const char* ga = (const char*)(Ab + (size_t)row * K + k0) + src_off;
      const char* gb = (const char*)(Bb + (size_t)row * K + k0) + src_off;
      __builtin_amdgcn_global_load_lds(
          (const __attribute__((address_space(1))) void*)ga,
          (__attribute__((address_space(3))) void*)(As + r0 * 128), 16, 0, 0);
      __builtin_amdgcn_global_load_lds(
          (const __attribute__((address_space(1))) void*)gb,
          (__attribute__((address_space(3))) void*)(Bs + r0 * 128), 16, 0, 0);
    }
    __syncthreads();
    for (int ks = 0; ks < 2; ++ks) {
      bf16x8 af[4], bfr[4];
      for (int f = 0; f < 4; ++f) {
        int m = wm + f * 16 + l16;
        af[f] = *reinterpret_cast<const bf16x8*>(As + m * 128 + ((ks * 64 + lhi * 16) ^ ((m & 7) << 4)));
        int n = wn + f * 16 + l16;
        bfr[f] = *reinterpret_cast<const bf16x8*>(Bs + n * 128 + ((ks * 64 + lhi * 16) ^ ((n & 7) << 4)));
      }
      for (int i = 0; i < 4; ++i)
        for (int j = 0; j < 4; ++j)
          acc[i][j] = __builtin_amdgcn_mfma_f32_16x16x32_bf16(af[i], bfr[j], acc[i][j], 0, 0, 0);
    }
    __syncthreads();
  }
  for (int i = 0; i < 4; ++i) {
    int m0 = bm * 128 + wm + i * 16 + lhi * 4;
    for (int j = 0; j < 4; ++j) {
      int n0 = bn * 128 + wn + j * 16 + l16;
      for (int r = 0; r < 4; ++r)
        C[(size_t)(m0 + r) * N + n0] = acc[i][j][r];
    }
  }
}

// ---------------- RoPE + row-norm capture ----------------
__global__ void k_rope(const float* __restrict__ pre, const float* __restrict__ cosT,
                       const float* __restrict__ sinT, u16* __restrict__ outb,
                       float* __restrict__ qn, u32* __restrict__ kn2max,
                       int nh, int rowstride) {
  int idx = blockIdx.x;          // (b*S + s)*nh + h
  int h = idx % nh;
  int bs = idx / nh;
  int b = bs / S_, s = bs % S_;
  int d = threadIdx.x;           // 0..63
  const float* row = pre + (size_t)bs * rowstride + h * HD_;
  const float* cr = cosT + (size_t)bs * HD_;
  const float* sr = sinT + (size_t)bs * HD_;
  float v1 = row[d], v2 = row[d + 64];
  float c1 = cr[d], s1 = sr[d], c2 = cr[d + 64], s2 = sr[d + 64];
  u16* out = outb + (((size_t)b * nh + h) * S_ + s) * HD_;
  out[d]      = f2b(v1 * c1 - v2 * s1);
  out[d + 64] = f2b(v2 * c2 + v1 * s2);
  float nr2 = v1 * v1 + v2 * v2;
  for (int o = 1; o < 64; o <<= 1) nr2 += __shfl_xor(nr2, o);
  if (d == 0) {
    if (qn)     qn[((size_t)b * nh + h) * S_ + s] = sqrtf(nr2);
    if (kn2max) atomicMax(&kn2max[b * nh + h], __builtin_bit_cast(u32, nr2));
  }
}

// ---------------- V: kvpre[B*S][1024] cols 512.. fp32 -> vT[(b*HKV+h)*128+d][S] bf16 ----------------
__global__ void k_vT(const float* __restrict__ kvpre, u16* __restrict__ vT) {
  __shared__ float t[32][33];
  int s0 = blockIdx.x * 32, d0 = blockIdx.y * 32;
  int bh = blockIdx.z;
  int b = bh >> 2, hk = bh & 3;
  int tx = threadIdx.x, ty = threadIdx.y;
  for (int j = ty; j < 32; j += 8)
    t[j][tx] = kvpre[((size_t)b * S_ + s0 + j) * 1024 + 512 + hk * HD_ + d0 + tx];
  __syncthreads();
  for (int j = ty; j < 32; j += 8)
    vT[((size_t)bh * HD_ + d0 + j) * S_ + s0 + tx] = f2b(t[tx][j]);
}

// ---------------- k_lsum: row sums of exp(QK^T*SCALE - M) over lower triangle ----------------
// Block = (bh, 128-row q-block). 4 waves (2q x 2k grid). Q frags persistent in regs,
// K tiles (64 x 128) block-shared in LDS via global_load_lds. One lsum write, no atomics.
__global__ __launch_bounds__(256, 2)
void k_lsum(const u16* __restrict__ qb_, const u16* __restrict__ kb_,
            const float* __restrict__ qn, const u32* __restrict__ knm,
            float* __restrict__ lsum) {
  __shared__ char Ks[16384];            // 64 rows x 256B
  __shared__ float red[4][64];
  const int tid = threadIdx.x;
  const int lane = tid & 63, wave = tid >> 6;
  const int l16 = lane & 15, lhi = lane >> 4;
  const int wq = (wave >> 1) * 64, wn2 = (wave & 1) * 32;
  const int qbi = 15 - (blockIdx.x >> 5);   // longest first
  const int bh = blockIdx.x & 31;
  const int b = bh >> 4, h = bh & 15, hk = h >> 2;
  const int q0 = qbi * 128, kend = q0 + 128;

  const u16* Q = qb_ + ((size_t)(b * H_ + h) * S_ + q0) * HD_;
  const u16* K = kb_ + (size_t)(b * HKV_ + hk) * S_ * HD_;

  bf16x8 qf[4][4];
  #pragma unroll
  for (int m = 0; m < 4; ++m) {
    const u16* qrow = Q + (size_t)(wq + 16 * m + l16) * HD_ + lhi * 8;
    #pragma unroll
    for (int ks = 0; ks < 4; ++ks)
      qf[m][ks] = *reinterpret_cast<const bf16x8*>(qrow + ks * 32);
  }
  const float kmax = sqrtf(__builtin_bit_cast(float, knm[b * HKV_ + hk]));
  float Mr[4][4];
  #pragma unroll
  for (int m = 0; m < 4; ++m)
    #pragma unroll
    for (int r = 0; r < 4; ++r)
      Mr[m][r] = SCALE_ * kmax * qn[(size_t)(b * H_ + h) * S_ + q0 + wq + 16 * m + 4 * lhi + r];

  float rs[4][4] = {};
  for (int kt = 0; kt < kend; kt += 64) {
    #pragma unroll
    for (int p = 0; p < 4; ++p) {
      int reg = wave + 4 * p;                 // wave-uniform 1KB region (4 rows)
      int row = reg * 4 + (lane >> 4);
      int src = ((lane & 15) * 16) ^ ((row & 7) << 4);
      __builtin_amdgcn_global_load_lds(
          (const __attribute__((address_space(1))) void*)((const char*)(K + (size_t)(kt + row) * HD_) + src),
          (__attribute__((address_space(3))) void*)(Ks + reg * 1024), 16, 0, 0);
    }
    __syncthreads();
    bf16x8 kf[2][4];
    #pragma unroll
    for (int n = 0; n < 2; ++n) {
      int row = wn2 + 16 * n + l16;
      #pragma unroll
      for (int ks = 0; ks < 4; ++ks)
        kf[n][ks] = *reinterpret_cast<const bf16x8*>(Ks + row * 256 + ((ks * 64 + lhi * 16) ^ ((row & 7) << 4)));
    }
    f32x4 sacc[4][2] = {};
    #pragma unroll
    for (int ks = 0; ks < 4; ++ks)
      #pragma unroll
      for (int m = 0; m < 4; ++m)
        #pragma unroll
        for (int n = 0; n < 2; ++n)
          sacc[m][n] = __builtin_amdgcn_mfma_f32_16x16x32_bf16(qf[m][ks], kf[n][ks], sacc[m][n], 0, 0, 0);
    bool mk = (kt >= q0);
    #pragma unroll
    for (int m = 0; m < 4; ++m)
      #pragma unroll
      for (int n = 0; n < 2; ++n)
        #pragma unroll
        for (int r = 0; r < 4; ++r) {
          float p = __expf(sacc[m][n][r] * SCALE_ - Mr[m][r]);
          if (mk) {
            int grow = q0 + wq + 16 * m + 4 * lhi + r;
            int gcol = kt + wn2 + 16 * n + l16;
            p = (gcol > grow) ? 0.f : p;
          }
          rs[m][r] += p;
        }
    __syncthreads();
  }
  #pragma unroll
  for (int m = 0; m < 4; ++m)
    #pragma unroll
    for (int r = 0; r < 4; ++r) {
      float s = rs[m][r];
      s += __shfl_xor(s, 1); s += __shfl_xor(s, 2);
      s += __shfl_xor(s, 4); s += __shfl_xor(s, 8);
      if (l16 == 0) red[wave][16 * m + 4 * lhi + r] = s;
    }
  __syncthreads();
  if (tid < 128) {
    int grp = tid >> 6, rid = tid & 63;
    lsum[(size_t)bh * S_ + q0 + grp * 64 + rid] = red[grp * 2][rid] + red[grp * 2 + 1][rid];
  }
}

// ---------------- k_fused: QK -> normalized P (single fp32 write) + PV -> oh ----------------
// Block = (bh, 128-row q-block), 4 waves. Per 64-k tile: stage K (16KB) + V^T (16KB)
// block-shared; QK MFMA (wave: 64q x 32k); p = exp(s*SCALE)*C_row (C = exp(-M)/lsum);
// fragment-store P to attn; bf16 P into swizzled 16KB LDS tile; PV MFMA (wave: 64q x 64d).
// Every block writes exactly 128x2048x4B = 1MB (P + zero-fill) -> write-balanced.
__global__ __launch_bounds__(256, 2)
void k_fused(const u16* __restrict__ qb_, const u16* __restrict__ kb_,
             const u16* __restrict__ vT, const float* __restrict__ qn,
             const u32* __restrict__ knm, const float* __restrict__ lsum,
             float* __restrict__ attn, u16* __restrict__ oh) {
  __shared__ char Ks[16384];   // 64 k-rows x 256B
  __shared__ char Vs[16384];   // 128 d-rows x 128B (V^T, 64 kcols)
  __shared__ char Ps[16384];   // 128 q-rows x 128B (bf16 P, 64 kcols, XOR-swizzled)
  const int tid = threadIdx.x;
  const int lane = tid & 63, wave = tid >> 6;
  const int l16 = lane & 15, lhi = lane >> 4;
  const int wq = (wave >> 1) * 64, wn2 = (wave & 1) * 32, wd = (wave & 1) * 64;
  const int qbi = 15 - (blockIdx.x >> 5);   // longest first
  const int bh = blockIdx.x & 31;
  const int b = bh >> 4, h = bh & 15, hk = h >> 2;
  const int q0 = qbi * 128, kend = q0 + 128;

  const u16* Q  = qb_ + ((size_t)(b * H_ + h) * S_ + q0) * HD_;
  const u16* K  = kb_ + (size_t)(b * HKV_ + hk) * S_ * HD_;
  const u16* Vt = vT + (size_t)(b * HKV_ + hk) * HD_ * S_;
  float* attnp = attn + ((size_t)bh * S_ + q0) * S_;   // rows local 0..127

  bf16x8 qf[4][4];
  #pragma unroll
  for (int m = 0; m < 4; ++m) {
    const u16* qrow = Q + (size_t)(wq + 16 * m + l16) * HD_ + lhi * 8;
    #pragma unroll
    for (int ks = 0; ks < 4; ++ks)
      qf[m][ks] = *reinterpret_cast<const bf16x8*>(qrow + ks * 32);
  }
  const float kmax = sqrtf(__builtin_bit_cast(float, knm[b * HKV_ + hk]));
  float Cr[4][4];
  #pragma unroll
  for (int m = 0; m < 4; ++m)
    #pragma unroll
    for (int r = 0; r < 4; ++r) {
      int grow = q0 + wq + 16 * m + 4 * lhi + r;
      float M = SCALE_ * kmax * qn[(size_t)(b * H_ + h) * S_ + grow];
      Cr[m][r] = __expf(-M) / lsum[(size_t)bh * S_ + grow];
    }

  f32x4 oacc[4][4] = {};
  for (int kt = 0; kt < kend; kt += 64) {
    // stage K: 16 x 1KB regions (4 rows x 256B)
    #pragma unroll
    for (int p = 0; p < 4; ++p) {
      int reg = wave + 4 * p;
      int row = reg * 4 + (lane >> 4);
      int src = ((lane & 15) * 16) ^ ((row & 7) << 4);
      __builtin_amdgcn_global_load_lds(
          (const __attribute__((address_space(1))) void*)((const char*)(K + (size_t)(kt + row) * HD_) + src),
          (__attribute__((address_space(3))) void*)(Ks + reg * 1024), 16, 0, 0);
    }
    // stage V^T: 16 x 1KB regions (8 rows x 128B)
    #pragma unroll
    for (int p = 0; p < 4; ++p) {
      int reg = wave + 4 * p;
      int row = reg * 8 + (lane >> 3);
      int src = ((lane & 7) * 16) ^ ((row & 7) << 4);
      __builtin_amdgcn_global_load_lds(
          (const __attribute__((address_space(1))) void*)((const char*)(Vt + (size_t)row * S_ + kt) + src),
          (__attribute__((address_space(3))) void*)(Vs + reg * 1024), 16, 0, 0);
    }
    __syncthreads();

    // QK: wave computes 64q x 32k
    bf16x8 kf[2][4];
    #pragma unroll
    for (int n = 0; n < 2; ++n) {
      int row = wn2 + 16 * n + l16;
      #pragma unroll
      for (int ks = 0; ks < 4; ++ks)
        kf[n][ks] = *reinterpret_cast<const bf16x8*>(Ks + row * 256 + ((ks * 64 + lhi * 16) ^ ((row & 7) << 4)));
    }
    f32x4 sacc[4][2] = {};
    #pragma unroll
    for (int ks = 0; ks < 4; ++ks)
      #pragma unroll
      for (int m = 0; m < 4; ++m)
        #pragma unroll
        for (int n = 0; n < 2; ++n)
          sacc[m][n] = __builtin_amdgcn_mfma_f32_16x16x32_bf16(qf[m][ks], kf[n][ks], sacc[m][n], 0, 0, 0);

    // normalize + the single P write (fp32) + bf16 into Ps
    bool mk = (kt >= q0);
    #pragma unroll
    for (int m = 0; m < 4; ++m)
      #pragma unroll
      for (int n = 0; n < 2; ++n)
        #pragma unroll
        for (int r = 0; r < 4; ++r) {
          int lrow = wq + 16 * m + 4 * lhi + r;
          int col = wn2 + 16 * n + l16;
          float p = __expf(sacc[m][n][r] * SCALE_) * Cr[m][r];
          if (mk) p = (kt + col > q0 + lrow) ? 0.f : p;
          attnp[(size_t)lrow * S_ + kt + col] = p;
          *reinterpret_cast<u16*>(Ps + lrow * 128 + ((col * 2) ^ ((lrow & 7) << 4))) = f2b(p);
        }
    __syncthreads();   // Ps complete (cross-wave)

    // PV: wave computes 64q x 64d
    #pragma unroll
    for (int ks = 0; ks < 2; ++ks) {
      bf16x8 pa[4], vf[4];
      #pragma unroll
      for (int m = 0; m < 4; ++m) {
        int lrow = wq + 16 * m + l16;
        pa[m] = *reinterpret_cast<const bf16x8*>(Ps + lrow * 128 + ((ks * 64 + lhi * 16) ^ ((lrow & 7) << 4)));
      }
      #pragma unroll
      for (int n = 0; n < 4; ++n) {
        int drow = wd + 16 * n + l16;
        vf[n] = *reinterpret_cast<const bf16x8*>(Vs + drow * 128 + ((ks * 64 + lhi * 16) ^ ((drow & 7) << 4)));
      }
      #pragma unroll
      for (int m = 0; m < 4; ++m)
        #pragma unroll
        for (int n = 0; n < 4; ++n)
          oacc[m][n] = __builtin_amdgcn_mfma_f32_16x16x32_bf16(pa[m], vf[n], oacc[m][n], 0, 0, 0);
    }
    __syncthreads();   // done reading Ks/Vs/Ps before next stage
  }

  // oh write: rows q0+wq+16m+4lhi+r, cols h*128 + wd+16n+l16
  #pragma unroll
  for (int m = 0; m < 4; ++m)
    #pragma unroll
    for (int n = 0; n < 4; ++n)
      #pragma unroll
      for (int r = 0; r < 4; ++r) {
        int grow = q0 + wq + 16 * m + 4 * lhi + r;
        oh[((size_t)b * S_ + grow) * (H_ * HD_) + h * HD_ + wd + 16 * n + l16] = f2b(oacc[m][n][r]);
      }

  // zero-fill cols [kend, S) for the block's 128 rows
  {
    f32x4 z = {0.f, 0.f, 0.f, 0.f};
    int lrow = tid >> 1;
    for (int c = kend + (tid & 1) * 4; c < S_; c += 8)
      *reinterpret_cast<f32x4*>(attnp + (size_t)lrow * S_ + c) = z;
  }
}

extern "C" void kernel_launch(void* const* d_in, const int* in_sizes, int n_in,
                              void* d_out, int out_size, void* d_ws, size_t ws_size,
                              hipStream_t stream) {
  const float* x    = (const float*)d_in[0];
  const float* cosT = (const float*)d_in[1];
  const float* sinT = (const float*)d_in[2];
  // d_in[3] = attention_mask: pure causal, reconstructed in-kernel
  const float* Wq = (const float*)d_in[4];
  const float* Wk = (const float*)d_in[5];
  const float* Wv = (const float*)d_in[6];
  const float* Wo = (const float*)d_in[7];
  float* out  = (float*)d_out;
  float* attn = out + (size_t)B_ * S_ * D_;

  char* ws = (char*)d_ws;
  u16*   xb    = (u16*)(ws);                       // 16,777,216 B
  u16*   wqT   = (u16*)(ws + 16777216);            //  8,388,608
  u16*   wkvT  = (u16*)(ws + 25165824);            //  4,194,304 (K rows 0..511, V rows 512..1023)
  u16*   woT   = (u16*)(ws + 29360128);            //  8,388,608
  float* qpre  = (float*)(ws + 37748736);          // 33,554,432
  float* kvpre = (float*)(ws + 71303168);          // 16,777,216
  u16*   qb    = (u16*)(ws + 88080384);            // 16,777,216
  u16*   kb    = (u16*)(ws + 104857600);           //  4,194,304
  u16*   vT    = (u16*)(ws + 109051904);           //  4,194,304
  u16*   oh    = (u16*)(ws + 113246208);           // 16,777,216
  float* lsum  = (float*)(ws + 130023424);         //    262,144 (B*H*S)
  u32*   knm   = (u32*)(ws + 130285568);           //         32
  // qn reuses xb region (xb dead after projection GEMMs; k_rope runs after)
  float* qn    = (float*)(ws);                     //    262,144

  // 1) dtype prep + init
  k_f2b<<<8192, 256, 0, stream>>>(x, xb);
  k_init8<<<1, 64, 0, stream>>>(knm);
  k_wT<<<dim3(64, 64), dim3(32, 8), 0, stream>>>(Wq, wqT, 2048, 2048);
  k_wT<<<dim3(16, 64), dim3(32, 8), 0, stream>>>(Wk, wkvT, 2048, 512);
  k_wT<<<dim3(16, 64), dim3(32, 8), 0, stream>>>(Wv, wkvT + (size_t)512 * 2048, 2048, 512);
  k_wT<<<dim3(64, 64), dim3(32, 8), 0, stream>>>(Wo, woT, 2048, 2048);

  // 2) projections: Q (N=2048) and fused K|V (N=1024)
  k_gemm<<<dim3(16, 32), 256, 0, stream>>>(xb, wqT, qpre, 4096, 2048, 2048);
  k_gemm<<<dim3(8, 32), 256, 0, stream>>>(xb, wkvT, kvpre, 4096, 1024, 2048);

  // 3) RoPE + layout conversion (+ norm capture); xb is free now
  k_rope<<<B_ * S_ * H_, 64, 0, stream>>>(qpre, cosT, sinT, qb, qn, nullptr, H_, 2048);
  k_rope<<<B_ * S_ * HKV_, 64, 0, stream>>>(kvpre, cosT, sinT, kb, nullptr, knm, HKV_, 1024);
  k_vT<<<dim3(64, 4, B_ * HKV_), dim3(32, 8), 0, stream>>>(kvpre, vT);

  // 4a) row-sum pass (no P write)
  k_lsum<<<512, 256, 0, stream>>>(qb, kb, qn, knm, lsum);

  // 4b) fused: normalized P written once + PV -> oh + zero-fill
  k_fused<<<512, 256, 0, stream>>>(qb, kb, vT, qn, knm, lsum, attn, oh);

  // 5) output projection
  k_gemm<<<dim3(16, 32), 256, 0, stream>>>(oh, woT, out, 4096, 2048, 2048);
}

// Round 7
// 650.245 us; speedup vs baseline: 1.2095x; 1.0432x over previous
//
#include <hip/hip_runtime.h>

// Problem constants
#define B_   2
#define S_   2048
#define D_   2048
#define H_   16
#define HKV_ 4
#define HD_  128
#define SCALE_ 0.08838834764831845f  // 128^-0.5

typedef unsigned short u16;
typedef unsigned int u32;
typedef __attribute__((ext_vector_type(4))) float  f32x4;
typedef __attribute__((ext_vector_type(8))) __bf16 bf16x8;

__device__ __forceinline__ u16 f2b(float f) {
  u32 u = __builtin_bit_cast(u32, f);
  u += 0x7fffu + ((u >> 16) & 1u);   // round-to-nearest-even
  return (u16)(u >> 16);
}
__device__ __forceinline__ float b2f(u16 v) {
  return __builtin_bit_cast(float, (u32)v << 16);
}

// ---------------- fp32 -> bf16 elementwise (x) + knm zero ----------------
__global__ void k_f2b(const float* __restrict__ in, u16* __restrict__ out,
                      u32* __restrict__ knm) {
  if (blockIdx.x == 0 && threadIdx.x < 8) knm[threadIdx.x] = 0u;
  size_t i = (size_t)blockIdx.x * 256 + threadIdx.x;
  float4 v = reinterpret_cast<const float4*>(in)[i];
  ushort4 o;
  o.x = f2b(v.x); o.y = f2b(v.y); o.z = f2b(v.z); o.w = f2b(v.w);
  reinterpret_cast<ushort4*>(out)[i] = o;
}

// ---------------- all four W[K=2048][N] fp32 -> Wt[N][K] bf16 ----------------
__global__ void k_wTall(const float* __restrict__ W0, const float* __restrict__ W1,
                        const float* __restrict__ W2, const float* __restrict__ W3,
                        u16* __restrict__ T0, u16* __restrict__ T1,
                        u16* __restrict__ T2, u16* __restrict__ T3) {
  __shared__ float t[32][33];
  const int z = blockIdx.z;
  const float* W = (z == 0) ? W0 : (z == 1) ? W1 : (z == 2) ? W2 : W3;
  u16* T = (z == 0) ? T0 : (z == 1) ? T1 : (z == 2) ? T2 : T3;
  const int N = (z == 0 || z == 3) ? 2048 : 512;
  const int K = 2048;
  int n0 = blockIdx.x * 32, k0 = blockIdx.y * 32;
  if (n0 >= N) return;
  int tx = threadIdx.x, ty = threadIdx.y;
  for (int j = ty; j < 32; j += 8)
    t[j][tx] = W[(size_t)(k0 + j) * N + n0 + tx];
  __syncthreads();
  for (int j = ty; j < 32; j += 8)
    T[(size_t)(n0 + j) * K + k0 + tx] = f2b(t[tx][j]);
}

// ---------------- GEMM: C[M][N] fp32 = A[M][K] bf16 * Bt[N][K] bf16 ----------------
__global__ __launch_bounds__(256, 3)
void k_gemm(const u16* __restrict__ A, const u16* __restrict__ Bt,
            float* __restrict__ C, int M, int N, int K) {
  __shared__ char smem[128 * 128 + 128 * 128];
  char* As = smem;
  char* Bs = smem + 128 * 128;
  const int tid = threadIdx.x;
  const int lane = tid & 63, wave = tid >> 6;
  const int l16 = lane & 15, lhi = lane >> 4;
  const int wm = (wave >> 1) * 64, wn = (wave & 1) * 64;
  const int bm = blockIdx.y, bn = blockIdx.x;
  const u16* Ab = A + (size_t)bm * 128 * K;
  const u16* Bb = Bt + (size_t)bn * 128 * K;
  f32x4 acc[4][4] = {};
  for (int k0 = 0; k0 < K; k0 += 64) {
    for (int p = 0; p < 4; ++p) {
      int r0 = wave * 32 + p * 8;
      int row = r0 + (lane >> 3);
      int src_off = ((lane & 7) * 16) ^ ((row & 7) << 4);
      const char* ga = (const char*)(Ab + (size_t)row * K + k0) + src_off;
      const char* gb = (const char*)(Bb + (size_t)row * K + k0) + src_off;
      __builtin_amdgcn_global_load_lds(
          (const __attribute__((address_space(1))) void*)ga,
          (__attribute__((address_space(3))) void*)(As + r0 * 128), 16, 0, 0);
      __builtin_amdgcn_global_load_lds(
          (const __attribute__((address_space(1))) void*)gb,
          (__attribute__((address_space(3))) void*)(Bs + r0 * 128), 16, 0, 0);
    }
    __syncthreads();
    for (int ks = 0; ks < 2; ++ks) {
      bf16x8 af[4], bfr[4];
      for (int f = 0; f < 4; ++f) {
        int m = wm + f * 16 + l16;
        af[f] = *reinterpret_cast<const bf16x8*>(As + m * 128 + ((ks * 64 + lhi * 16) ^ ((m & 7) << 4)));
        int n = wn + f * 16 + l16;
        bfr[f] = *reinterpret_cast<const bf16x8*>(Bs + n * 128 + ((ks * 64 + lhi * 16) ^ ((n & 7) << 4)));
      }
      for (int i = 0; i < 4; ++i)
        for (int j = 0; j < 4; ++j)
          acc[i][j] = __builtin_amdgcn_mfma_f32_16x16x32_bf16(af[i], bfr[j], acc[i][j], 0, 0, 0);
    }
    __syncthreads();
  }
  // C write via LDS bounce: two 64-col halves, 256B/row contiguous stores
  for (int ch = 0; ch < 2; ++ch) {
    __syncthreads();
    if ((wave & 1) == ch) {
      #pragma unroll
      for (int i = 0; i < 4; ++i)
        #pragma unroll
        for (int j = 0; j < 4; ++j)
          #pragma unroll
          for (int r = 0; r < 4; ++r) {
            int lrow = wm + i * 16 + lhi * 4 + r;   // 0..127
            int lcol = j * 16 + l16;                 // 0..63
            *reinterpret_cast<float*>(smem + (size_t)(lrow * 64 + lcol) * 4) = acc[i][j][r];
          }
    }
    __syncthreads();
    int rbase = wave * 32 + (lane >> 3);
    int c0 = (lane & 7) * 8;
    #pragma unroll
    for (int i = 0; i < 4; ++i) {
      int rr = rbase + 8 * i;
      const float* src = reinterpret_cast<const float*>(smem + (size_t)(rr * 64 + c0) * 4);
      float4 w0 = *reinterpret_cast<const float4*>(src);
      float4 w1 = *reinterpret_cast<const float4*>(src + 4);
      float* dst = C + (size_t)(bm * 128 + rr) * N + bn * 128 + ch * 64 + c0;
      *reinterpret_cast<float4*>(dst)     = w0;
      *reinterpret_cast<float4*>(dst + 4) = w1;
    }
  }
}

// ---------------- RoPE (Q and K fused) + row-norm capture ----------------
// 4 waves/block, one (b,s,h) row per wave.
__global__ void k_rope2(const float* __restrict__ qpre, const float* __restrict__ kvpre,
                        const float* __restrict__ cosT, const float* __restrict__ sinT,
                        u16* __restrict__ qbo, u16* __restrict__ kbo,
                        float* __restrict__ qn, u32* __restrict__ knm) {
  int idx = blockIdx.x * 4 + (threadIdx.x >> 6);
  int d = threadIdx.x & 63;
  const float* pre; u16* outb; int nh, rowstride; bool isq;
  if (idx < B_ * S_ * H_) {
    pre = qpre; outb = qbo; nh = H_; rowstride = 2048; isq = true;
  } else {
    idx -= B_ * S_ * H_;
    pre = kvpre; outb = kbo; nh = HKV_; rowstride = 1024; isq = false;
  }
  int h = idx % nh;
  int bs = idx / nh;
  int b = bs / S_, s = bs % S_;
  const float* row = pre + (size_t)bs * rowstride + h * HD_;
  const float* cr = cosT + (size_t)bs * HD_;
  const float* sr = sinT + (size_t)bs * HD_;
  float v1 = row[d], v2 = row[d + 64];
  float c1 = cr[d], s1 = sr[d], c2 = cr[d + 64], s2 = sr[d + 64];
  u16* out = outb + (((size_t)b * nh + h) * S_ + s) * HD_;
  out[d]      = f2b(v1 * c1 - v2 * s1);
  out[d + 64] = f2b(v2 * c2 + v1 * s2);
  float nr2 = v1 * v1 + v2 * v2;
  for (int o = 1; o < 64; o <<= 1) nr2 += __shfl_xor(nr2, o);
  if (d == 0) {
    if (isq) qn[((size_t)b * nh + h) * S_ + s] = sqrtf(nr2);
    else     atomicMax(&knm[b * nh + h], __builtin_bit_cast(u32, nr2));
  }
}

// ---------------- V: kvpre[B*S][1024] cols 512.. fp32 -> vT[(b*HKV+h)*128+d][S] bf16 ----------------
__global__ void k_vT(const float* __restrict__ kvpre, u16* __restrict__ vT) {
  __shared__ float t[32][33];
  int s0 = blockIdx.x * 32, d0 = blockIdx.y * 32;
  int bh = blockIdx.z;
  int b = bh >> 2, hk = bh & 3;
  int tx = threadIdx.x, ty = threadIdx.y;
  for (int j = ty; j < 32; j += 8)
    t[j][tx] = kvpre[((size_t)b * S_ + s0 + j) * 1024 + 512 + hk * HD_ + d0 + tx];
  __syncthreads();
  for (int j = ty; j < 32; j += 8)
    vT[((size_t)bh * HD_ + d0 + j) * S_ + s0 + tx] = f2b(t[tx][j]);
}

// Balanced block mapping: CU pairs get qbi v and 15-v (pairing long+short).
__device__ __forceinline__ void map_block(int bid, int& qbi, int& bh) {
  int hi = bid >> 8, lo = bid & 255;
  qbi = hi ? 15 - (lo & 15) : (lo & 15);
  bh = ((lo >> 4) << 1) | hi;
}

// ---------------- k_lsum: row sums of exp(QK^T*SCALE - M) over lower triangle ----------------
__global__ __launch_bounds__(256, 2)
void k_lsum(const u16* __restrict__ qb_, const u16* __restrict__ kb_,
            const float* __restrict__ qn, const u32* __restrict__ knm,
            float* __restrict__ lsum) {
  __shared__ char Ks[16384];            // 64 rows x 256B
  __shared__ float red[4][64];
  const int tid = threadIdx.x;
  const int lane = tid & 63, wave = tid >> 6;
  const int l16 = lane & 15, lhi = lane >> 4;
  const int wq = (wave >> 1) * 64, wn2 = (wave & 1) * 32;
  int qbi, bh;
  map_block(blockIdx.x, qbi, bh);
  const int b = bh >> 4, h = bh & 15, hk = h >> 2;
  const int q0 = qbi * 128, kend = q0 + 128;

  const u16* Q = qb_ + ((size_t)(b * H_ + h) * S_ + q0) * HD_;
  const u16* K = kb_ + (size_t)(b * HKV_ + hk) * S_ * HD_;

  bf16x8 qf[4][4];
  #pragma unroll
  for (int m = 0; m < 4; ++m) {
    const u16* qrow = Q + (size_t)(wq + 16 * m + l16) * HD_ + lhi * 8;
    #pragma unroll
    for (int ks = 0; ks < 4; ++ks)
      qf[m][ks] = *reinterpret_cast<const bf16x8*>(qrow + ks * 32);
  }
  const float kmax = sqrtf(__builtin_bit_cast(float, knm[b * HKV_ + hk]));
  float Mr[4][4];
  #pragma unroll
  for (int m = 0; m < 4; ++m)
    #pragma unroll
    for (int r = 0; r < 4; ++r)
      Mr[m][r] = SCALE_ * kmax * qn[(size_t)(b * H_ + h) * S_ + q0 + wq + 16 * m + 4 * lhi + r];

  float rs[4][4] = {};
  for (int kt = 0; kt < kend; kt += 64) {
    #pragma unroll
    for (int p = 0; p < 4; ++p) {
      int reg = wave + 4 * p;
      int row = reg * 4 + (lane >> 4);
      int src = ((lane & 15) * 16) ^ ((row & 7) << 4);
      __builtin_amdgcn_global_load_lds(
          (const __attribute__((address_space(1))) void*)((const char*)(K + (size_t)(kt + row) * HD_) + src),
          (__attribute__((address_space(3))) void*)(Ks + reg * 1024), 16, 0, 0);
    }
    __syncthreads();
    bf16x8 kf[2][4];
    #pragma unroll
    for (int n = 0; n < 2; ++n) {
      int row = wn2 + 16 * n + l16;
      #pragma unroll
      for (int ks = 0; ks < 4; ++ks)
        kf[n][ks] = *reinterpret_cast<const bf16x8*>(Ks + row * 256 + ((ks * 64 + lhi * 16) ^ ((row & 7) << 4)));
    }
    f32x4 sacc[4][2] = {};
    #pragma unroll
    for (int ks = 0; ks < 4; ++ks)
      #pragma unroll
      for (int m = 0; m < 4; ++m)
        #pragma unroll
        for (int n = 0; n < 2; ++n)
          sacc[m][n] = __builtin_amdgcn_mfma_f32_16x16x32_bf16(qf[m][ks], kf[n][ks], sacc[m][n], 0, 0, 0);
    bool mk = (kt >= q0);
    #pragma unroll
    for (int m = 0; m < 4; ++m)
      #pragma unroll
      for (int n = 0; n < 2; ++n)
        #pragma unroll
        for (int r = 0; r < 4; ++r) {
          float p = __expf(sacc[m][n][r] * SCALE_ - Mr[m][r]);
          if (mk) {
            int grow = q0 + wq + 16 * m + 4 * lhi + r;
            int gcol = kt + wn2 + 16 * n + l16;
            p = (gcol > grow) ? 0.f : p;
          }
          rs[m][r] += p;
        }
    __syncthreads();
  }
  #pragma unroll
  for (int m = 0; m < 4; ++m)
    #pragma unroll
    for (int r = 0; r < 4; ++r) {
      float s = rs[m][r];
      s += __shfl_xor(s, 1); s += __shfl_xor(s, 2);
      s += __shfl_xor(s, 4); s += __shfl_xor(s, 8);
      if (l16 == 0) red[wave][16 * m + 4 * lhi + r] = s;
    }
  __syncthreads();
  if (tid < 128) {
    int grp = tid >> 6, rid = tid & 63;
    lsum[(size_t)bh * S_ + q0 + grp * 64 + rid] = red[grp * 2][rid] + red[grp * 2 + 1][rid];
  }
}

// ---------------- k_fused: QK -> normalized P (single coalesced write) + PV -> oh ----------------
__global__ __launch_bounds__(256, 2)
void k_fused(const u16* __restrict__ qb_, const u16* __restrict__ kb_,
             const u16* __restrict__ vT, const float* __restrict__ qn,
             const u32* __restrict__ knm, const float* __restrict__ lsum,
             float* __restrict__ attn, u16* __restrict__ oh) {
  __shared__ char Ks[16384];   // 64 k-rows x 256B
  __shared__ char Vs[16384];   // 128 d-rows x 128B
  __shared__ char Ps[16384];   // 128 q-rows x 128B (bf16 P, swizzled)
  const int tid = threadIdx.x;
  const int lane = tid & 63, wave = tid >> 6;
  const int l16 = lane & 15, lhi = lane >> 4;
  const int wq = (wave >> 1) * 64, wn2 = (wave & 1) * 32, wd = (wave & 1) * 64;
  int qbi, bh;
  map_block(blockIdx.x, qbi, bh);
  const int b = bh >> 4, h = bh & 15, hk = h >> 2;
  const int q0 = qbi * 128, kend = q0 + 128;

  const u16* Q  = qb_ + ((size_t)(b * H_ + h) * S_ + q0) * HD_;
  const u16* K  = kb_ + (size_t)(b * HKV_ + hk) * S_ * HD_;
  const u16* Vt = vT + (size_t)(b * HKV_ + hk) * HD_ * S_;
  float* attnp = attn + ((size_t)bh * S_ + q0) * S_;   // local rows 0..127

  bf16x8 qf[4][4];
  #pragma unroll
  for (int m = 0; m < 4; ++m) {
    const u16* qrow = Q + (size_t)(wq + 16 * m + l16) * HD_ + lhi * 8;
    #pragma unroll
    for (int ks = 0; ks < 4; ++ks)
      qf[m][ks] = *reinterpret_cast<const bf16x8*>(qrow + ks * 32);
  }
  const float kmax = sqrtf(__builtin_bit_cast(float, knm[b * HKV_ + hk]));
  float Cr[4][4];
  #pragma unroll
  for (int m = 0; m < 4; ++m)
    #pragma unroll
    for (int r = 0; r < 4; ++r) {
      int grow = q0 + wq + 16 * m + 4 * lhi + r;
      float M = SCALE_ * kmax * qn[(size_t)(b * H_ + h) * S_ + grow];
      Cr[m][r] = __expf(-M) / lsum[(size_t)bh * S_ + grow];
    }

  f32x4 oacc[4][4] = {};
  for (int kt = 0; kt < kend; kt += 64) {
    // stage K (16KB) + V^T (16KB), block-shared
    #pragma unroll
    for (int p = 0; p < 4; ++p) {
      int reg = wave + 4 * p;
      int row = reg * 4 + (lane >> 4);
      int src = ((lane & 15) * 16) ^ ((row & 7) << 4);
      __builtin_amdgcn_global_load_lds(
          (const __attribute__((address_space(1))) void*)((const char*)(K + (size_t)(kt + row) * HD_) + src),
          (__attribute__((address_space(3))) void*)(Ks + reg * 1024), 16, 0, 0);
    }
    #pragma unroll
    for (int p = 0; p < 4; ++p) {
      int reg = wave + 4 * p;
      int row = reg * 8 + (lane >> 3);
      int src = ((lane & 7) * 16) ^ ((row & 7) << 4);
      __builtin_amdgcn_global_load_lds(
          (const __attribute__((address_space(1))) void*)((const char*)(Vt + (size_t)row * S_ + kt) + src),
          (__attribute__((address_space(3))) void*)(Vs + reg * 1024), 16, 0, 0);
    }
    __syncthreads();

    // QK: wave computes 64q x 32k
    bf16x8 kf[2][4];
    #pragma unroll
    for (int n = 0; n < 2; ++n) {
      int row = wn2 + 16 * n + l16;
      #pragma unroll
      for (int ks = 0; ks < 4; ++ks)
        kf[n][ks] = *reinterpret_cast<const bf16x8*>(Ks + row * 256 + ((ks * 64 + lhi * 16) ^ ((row & 7) << 4)));
    }
    f32x4 sacc[4][2] = {};
    #pragma unroll
    for (int ks = 0; ks < 4; ++ks)
      #pragma unroll
      for (int m = 0; m < 4; ++m)
        #pragma unroll
        for (int n = 0; n < 2; ++n)
          sacc[m][n] = __builtin_amdgcn_mfma_f32_16x16x32_bf16(qf[m][ks], kf[n][ks], sacc[m][n], 0, 0, 0);

    // normalized p -> Ps (bf16, swizzled); no global stores here
    bool mk = (kt >= q0);
    #pragma unroll
    for (int m = 0; m < 4; ++m)
      #pragma unroll
      for (int n = 0; n < 2; ++n)
        #pragma unroll
        for (int r = 0; r < 4; ++r) {
          int lrow = wq + 16 * m + 4 * lhi + r;
          int col = wn2 + 16 * n + l16;
          float p = __expf(sacc[m][n][r] * SCALE_) * Cr[m][r];
          if (mk) p = (kt + col > q0 + lrow) ? 0.f : p;
          *reinterpret_cast<u16*>(Ps + lrow * 128 + ((col * 2) ^ ((lrow & 7) << 4))) = f2b(p);
        }
    __syncthreads();   // Ps complete (cross-wave)

    // PV: wave computes 64q x 64d
    #pragma unroll
    for (int ks = 0; ks < 2; ++ks) {
      bf16x8 pa[4], vf[4];
      #pragma unroll
      for (int m = 0; m < 4; ++m) {
        int lrow = wq + 16 * m + l16;
        pa[m] = *reinterpret_cast<const bf16x8*>(Ps + lrow * 128 + ((ks * 64 + lhi * 16) ^ ((lrow & 7) << 4)));
      }
      #pragma unroll
      for (int n = 0; n < 4; ++n) {
        int drow = wd + 16 * n + l16;
        vf[n] = *reinterpret_cast<const bf16x8*>(Vs + drow * 128 + ((ks * 64 + lhi * 16) ^ ((drow & 7) << 4)));
      }
      #pragma unroll
      for (int m = 0; m < 4; ++m)
        #pragma unroll
        for (int n = 0; n < 4; ++n)
          oacc[m][n] = __builtin_amdgcn_mfma_f32_16x16x32_bf16(pa[m], vf[n], oacc[m][n], 0, 0, 0);
    }

    // coalesced attn write from Ps: 32 rows/wave, 256B/row contiguity
    {
      int rbase = wave * 32 + (lane >> 3);
      int c0 = (lane & 7) * 8;
      #pragma unroll
      for (int i = 0; i < 4; ++i) {
        int row = rbase + 8 * i;
        bf16x8 pv8 = *reinterpret_cast<const bf16x8*>(Ps + row * 128 + ((c0 * 2) ^ ((row & 7) << 4)));
        const u16* pu = reinterpret_cast<const u16*>(&pv8);
        float4 w0, w1;
        w0.x = b2f(pu[0]); w0.y = b2f(pu[1]); w0.z = b2f(pu[2]); w0.w = b2f(pu[3]);
        w1.x = b2f(pu[4]); w1.y = b2f(pu[5]); w1.z = b2f(pu[6]); w1.w = b2f(pu[7]);
        float* dst = attnp + (size_t)row * S_ + kt + c0;
        *reinterpret_cast<float4*>(dst)     = w0;
        *reinterpret_cast<float4*>(dst + 4) = w1;
      }
    }
    __syncthreads();   // all Ks/Vs/Ps reads done before next stage
  }

  // oh write via Ps bounce: two 64-col halves, 128B/row contiguity
  #pragma unroll
  for (int dh = 0; dh < 2; ++dh) {
    __syncthreads();
    if ((wave & 1) == dh) {
      #pragma unroll
      for (int m = 0; m < 4; ++m)
        #pragma unroll
        for (int n = 0; n < 4; ++n)
          #pragma unroll
          for (int r = 0; r < 4; ++r) {
            int lrow = wq + 16 * m + 4 * lhi + r;
            int lcol = 16 * n + l16;
            *reinterpret_cast<u16*>(Ps + lrow * 128 + lcol * 2) = f2b(oacc[m][n][r]);
          }
    }
    __syncthreads();
    int rbase = wave * 32 + (lane >> 3);
    int c0 = (lane & 7) * 8;
    #pragma unroll
    for (int i = 0; i < 4; ++i) {
      int row = rbase + 8 * i;
      bf16x8 v = *reinterpret_cast<const bf16x8*>(Ps + row * 128 + c0 * 2);
      *reinterpret_cast<bf16x8*>(oh + ((size_t)b * S_ + q0 + row) * (H_ * HD_) + h * HD_ + dh * 64 + c0) = v;
    }
  }

  // zero-fill cols [kend, S): 1KB contiguous per wave instruction
  {
    f32x4 z = {0.f, 0.f, 0.f, 0.f};
    for (int row = wave; row < 128; row += 4)
      for (int c = kend + lane * 4; c < S_; c += 256)
        *reinterpret_cast<f32x4*>(attnp + (size_t)row * S_ + c) = z;
  }
}

extern "C" void kernel_launch(void* const* d_in, const int* in_sizes, int n_in,
                              void* d_out, int out_size, void* d_ws, size_t ws_size,
                              hipStream_t stream) {
  const float* x    = (const float*)d_in[0];
  const float* cosT = (const float*)d_in[1];
  const float* sinT = (const float*)d_in[2];
  // d_in[3] = attention_mask: pure causal, reconstructed in-kernel
  const float* Wq = (const float*)d_in[4];
  const float* Wk = (const float*)d_in[5];
  const float* Wv = (const float*)d_in[6];
  const float* Wo = (const float*)d_in[7];
  float* out  = (float*)d_out;
  float* attn = out + (size_t)B_ * S_ * D_;

  char* ws = (char*)d_ws;
  u16*   xb    = (u16*)(ws);                       // 16,777,216 B
  u16*   wqT   = (u16*)(ws + 16777216);            //  8,388,608
  u16*   wkvT  = (u16*)(ws + 25165824);            //  4,194,304 (K rows 0..511, V rows 512..1023)
  u16*   woT   = (u16*)(ws + 29360128);            //  8,388,608
  float* qpre  = (float*)(ws + 37748736);          // 33,554,432
  float* kvpre = (float*)(ws + 71303168);          // 16,777,216
  u16*   qb    = (u16*)(ws + 88080384);            // 16,777,216
  u16*   kb    = (u16*)(ws + 104857600);           //  4,194,304
  u16*   vT    = (u16*)(ws + 109051904);           //  4,194,304
  u16*   oh    = (u16*)(ws + 113246208);           // 16,777,216
  float* lsum  = (float*)(ws + 130023424);         //    262,144 (B*H*S)
  u32*   knm   = (u32*)(ws + 130285568);           //         32
  // qn reuses xb region (xb dead after projection GEMMs; k_rope2 runs after)
  float* qn    = (float*)(ws);                     //    262,144

  // 1) dtype prep (+ knm zero)
  k_f2b<<<8192, 256, 0, stream>>>(x, xb, knm);
  k_wTall<<<dim3(64, 64, 4), dim3(32, 8), 0, stream>>>(Wq, Wk, Wv, Wo, wqT, wkvT,
                                                       wkvT + (size_t)512 * 2048, woT);

  // 2) projections: Q (N=2048) and fused K|V (N=1024)
  k_gemm<<<dim3(16, 32), 256, 0, stream>>>(xb, wqT, qpre, 4096, 2048, 2048);
  k_gemm<<<dim3(8, 32), 256, 0, stream>>>(xb, wkvT, kvpre, 4096, 1024, 2048);

  // 3) RoPE Q+K (+ norm capture; xb free now) and V transpose
  k_rope2<<<(B_ * S_ * (H_ + HKV_)) / 4, 256, 0, stream>>>(qpre, kvpre, cosT, sinT,
                                                           qb, kb, qn, knm);
  k_vT<<<dim3(64, 4, B_ * HKV_), dim3(32, 8), 0, stream>>>(kvpre, vT);

  // 4a) row-sum pass (no P write)
  k_lsum<<<512, 256, 0, stream>>>(qb, kb, qn, knm, lsum);

  // 4b) fused: normalized P written once (coalesced) + PV -> oh + zero-fill
  k_fused<<<512, 256, 0, stream>>>(qb, kb, vT, qn, knm, lsum, attn, oh);

  // 5) output projection
  k_gemm<<<dim3(16, 32), 256, 0, stream>>>(oh, woT, out, 4096, 2048, 2048);
}